// Round 11
// baseline (876.407 us; speedup 1.0000x reference)
//
#include <hip/hip_runtime.h>
#include <math.h>
#include <stdint.h>

#define N_NODES 50000
#define NPAD    50048            // 391 * 128
#define N_EDGES 800000
#define EP      (N_EDGES + N_NODES)   // 850000 edges incl self-loops
#define G_GRAPHS 256
#define BN_EPS   1e-5f
#define NEG_SLOPE 0.2f

typedef float f32x4 __attribute__((ext_vector_type(4)));
typedef _Float16 h16x8 __attribute__((ext_vector_type(8)));

static __device__ __forceinline__ float lrelu(float x) {
    return x > 0.f ? x : NEG_SLOPE * x;
}

static __device__ __forceinline__ void gld_lds16(const void* g, void* l) {
    __builtin_amdgcn_global_load_lds((const __attribute__((address_space(1))) void*)g,
                                     (__attribute__((address_space(3))) void*)l, 16, 0, 0);
}

static __device__ __forceinline__ float2 h2f2(unsigned u) {
    union { unsigned u; _Float16 h[2]; } c;
    c.u = u;
    return make_float2((float)c.h[0], (float)c.h[1]);
}

// ---------------------------------------------------------------- CSR build
__global__ void k_hist(const int* __restrict__ ei, int* __restrict__ deg) {
    int stride = gridDim.x * blockDim.x;
    for (int e = blockIdx.x * blockDim.x + threadIdx.x; e < EP; e += stride) {
        int d = (e < N_EDGES) ? ei[N_EDGES + e] : (e - N_EDGES);
        atomicAdd(&deg[d], 1);
    }
}

__global__ void k_scan1(const int* __restrict__ deg, int* __restrict__ row_start,
                        int* __restrict__ totals) {
    __shared__ int buf[1024];
    int t = threadIdx.x;
    int i = blockIdx.x * 1024 + t;
    int v = (i < N_NODES) ? deg[i] : 0;
    buf[t] = v;
    __syncthreads();
    for (int off = 1; off < 1024; off <<= 1) {
        int add = (t >= off) ? buf[t - off] : 0;
        __syncthreads();
        buf[t] += add;
        __syncthreads();
    }
    if (i < N_NODES) row_start[i] = buf[t] - v;     // exclusive
    if (t == 1023) totals[blockIdx.x] = buf[t];
}

__global__ void k_scan2(int* __restrict__ totals, int nb) {
    if (threadIdx.x == 0 && blockIdx.x == 0) {
        int run = 0;
        for (int i = 0; i < nb; ++i) { int v = totals[i]; totals[i] = run; run += v; }
    }
}

__global__ void k_scan3(int* __restrict__ row_start, const int* __restrict__ totals) {
    int i = blockIdx.x * blockDim.x + threadIdx.x;
    if (i < N_NODES) row_start[i] += totals[i >> 10];
    if (i == 0) row_start[N_NODES] = EP;
}

__global__ void k_scatter(const int* __restrict__ ei, const int* __restrict__ row_start,
                          int* __restrict__ cursor, int* __restrict__ csr_src) {
    int stride = gridDim.x * blockDim.x;
    for (int e = blockIdx.x * blockDim.x + threadIdx.x; e < EP; e += stride) {
        int s, d;
        if (e < N_EDGES) { s = ei[e]; d = ei[N_EDGES + e]; }
        else             { s = d = e - N_EDGES; }
        int pos = row_start[d] + atomicAdd(&cursor[d], 1);
        csr_src[pos] = s;
    }
}

// ---------------------------------------------------------------- weight convert, dest-linear:
// thread owns 8 consecutive dest f16 (coalesced 16B store); reads 8 coalesced-across-lanes
// fp32 rounds from W [K,Nc].
__global__ void k_cvtW(const float* __restrict__ W, _Float16* __restrict__ bthi,
                       int Nc, int lgKS) {
    int idx8 = blockIdx.x * 256 + threadIdx.x;
    int KS = 1 << lgKS;
    int total = ((KS << 5) * Nc) >> 3;
    if (idx8 >= total) return;
    int col = idx8 & 127;
    int kq  = (idx8 >> 7) & 3;
    int cs  = idx8 >> 9;
    int ks  = cs & (KS - 1);
    int c   = cs >> lgKS;
    int n = (c << 7) + col;
    int k = (ks << 5) + (kq << 3);
    union { _Float16 h[8]; uint4 u; } pk;
    #pragma unroll
    for (int j = 0; j < 8; ++j)
        pk.h[j] = (_Float16)W[(size_t)(k + j) * Nc + n];
    *(uint4*)&bthi[(size_t)idx8 * 8] = pk.u;
}

// ---------------------------------------------------------------- BN scale/shift prep (tiny)
__global__ void k_bnprep(const float* __restrict__ bnsum, const float* __restrict__ bnsq,
                         const float* __restrict__ gamma, const float* __restrict__ beta,
                         float* __restrict__ scale, float* __restrict__ shift, int W) {
    int f = blockIdx.x * 256 + threadIdx.x;
    if (f >= W) return;
    const float invN = 1.f / (float)N_NODES;
    float mean = bnsum[f] * invN;
    float var  = bnsq[f] * invN - mean * mean;
    float sc = gamma[f] * rsqrtf(var + BN_EPS);
    scale[f] = sc;
    shift[f] = beta[f] - mean * sc;
}

// ---------------------------------------------------------------- A prep, dest-linear: fp32 x -> f16 swizzled
__global__ void k_prepA0(const float* __restrict__ x, _Float16* __restrict__ Aswz,
                         int K, int lgKS) {
    int idx8 = blockIdx.x * 256 + threadIdx.x;
    int total = NPAD * (K >> 3);
    if (idx8 >= total) return;
    int row = idx8 & 127;
    int kq  = (idx8 >> 7) & 3;
    int cs  = idx8 >> 9;
    int ks  = cs & ((1 << lgKS) - 1);
    int rb  = cs >> lgKS;
    int r = (rb << 7) + row;
    int k = (ks << 5) + (kq << 3);
    union { _Float16 h[8]; uint4 u; } pk;
    if (r < N_NODES) {
        float4 a0 = *(const float4*)&x[(size_t)r * K + k];
        float4 a1 = *(const float4*)&x[(size_t)r * K + k + 4];
        pk.h[0]=(_Float16)a0.x; pk.h[1]=(_Float16)a0.y; pk.h[2]=(_Float16)a0.z; pk.h[3]=(_Float16)a0.w;
        pk.h[4]=(_Float16)a1.x; pk.h[5]=(_Float16)a1.y; pk.h[6]=(_Float16)a1.z; pk.h[7]=(_Float16)a1.w;
    } else {
        pk.u.x = pk.u.y = pk.u.z = pk.u.w = 0u;
    }
    *(uint4*)&Aswz[(size_t)idx8 * 8] = pk.u;
}

// ---------------------------------------------------------------- A prep, dest-linear: fp16 act + BN + ELU
__global__ void k_prepA1(const _Float16* __restrict__ act, const float* __restrict__ scale,
                         const float* __restrict__ shift, _Float16* __restrict__ Aswz,
                         int K, int lgKS) {
    int idx8 = blockIdx.x * 256 + threadIdx.x;
    int total = NPAD * (K >> 3);
    if (idx8 >= total) return;
    int row = idx8 & 127;
    int kq  = (idx8 >> 7) & 3;
    int cs  = idx8 >> 9;
    int ks  = cs & ((1 << lgKS) - 1);
    int rb  = cs >> lgKS;
    int r = (rb << 7) + row;
    int k = (ks << 5) + (kq << 3);
    union { _Float16 h[8]; uint4 u; } pk;
    if (r < N_NODES) {
        uint4 v = *(const uint4*)&act[(size_t)r * K + k];
        // k is wave-uniform -> these 4 float4 loads broadcast from L1
        float4 sc0 = *(const float4*)&scale[k];
        float4 sc1 = *(const float4*)&scale[k + 4];
        float4 sh0 = *(const float4*)&shift[k];
        float4 sh1 = *(const float4*)&shift[k + 4];
        float2 p0 = h2f2(v.x), p1 = h2f2(v.y), p2 = h2f2(v.z), p3 = h2f2(v.w);
        float y;
        y = fmaf(p0.x, sc0.x, sh0.x); pk.h[0] = (_Float16)(y > 0.f ? y : expm1f(y));
        y = fmaf(p0.y, sc0.y, sh0.y); pk.h[1] = (_Float16)(y > 0.f ? y : expm1f(y));
        y = fmaf(p1.x, sc0.z, sh0.z); pk.h[2] = (_Float16)(y > 0.f ? y : expm1f(y));
        y = fmaf(p1.y, sc0.w, sh0.w); pk.h[3] = (_Float16)(y > 0.f ? y : expm1f(y));
        y = fmaf(p2.x, sc1.x, sh1.x); pk.h[4] = (_Float16)(y > 0.f ? y : expm1f(y));
        y = fmaf(p2.y, sc1.y, sh1.y); pk.h[5] = (_Float16)(y > 0.f ? y : expm1f(y));
        y = fmaf(p3.x, sc1.z, sh1.z); pk.h[6] = (_Float16)(y > 0.f ? y : expm1f(y));
        y = fmaf(p3.y, sc1.w, sh1.w); pk.h[7] = (_Float16)(y > 0.f ? y : expm1f(y));
    } else {
        pk.u.x = pk.u.y = pk.u.z = pk.u.w = 0u;
    }
    *(uint4*)&Aswz[(size_t)idx8 * 8] = pk.u;
}

// ---------------------------------------------------------------- f16 single-pass MFMA GEMM,
// double-buffered LDS + counted vmcnt (prefetch stays in flight across MFMA).
__launch_bounds__(256)
__global__ void k_gemm_f16(const _Float16* __restrict__ Aswz, const _Float16* __restrict__ bthi,
                           _Float16* __restrict__ C2,
                           float* __restrict__ sSg, float* __restrict__ sDg,
                           const float* __restrict__ asr, const float* __restrict__ adr,
                           int M, int K, int Nc) {
    __shared__ _Float16 Ah[2][4096], Bh[2][4096];   // 32 KB double-buffered
    __shared__ float rS[128], rD[128];
    const int t    = threadIdx.x;
    const int lane = t & 63, wv = t >> 6;
    const int wr = wv >> 1, wc = wv & 1;
    const int lr = lane & 15, kq = lane >> 4;
    const int r0 = blockIdx.x * 128, c0 = blockIdx.y * 128;
    const int KS = K >> 5;
    const int H = Nc >> 7;
    const int head = blockIdx.y;

    const size_t achunk0 = (size_t)blockIdx.x * KS * 4096;
    const size_t bchunk0 = (size_t)blockIdx.y * KS * 4096;
    const int ge0 = wv * 512 + lane * 8;
    const int le0 = wv * 512;

    f32x4 acc[4][4];
    #pragma unroll
    for (int m = 0; m < 4; ++m)
        #pragma unroll
        for (int n = 0; n < 4; ++n) {
            acc[m][n][0] = 0.f; acc[m][n][1] = 0.f;
            acc[m][n][2] = 0.f; acc[m][n][3] = 0.f;
        }

    // prologue: issue tile 0 into buffer 0 (4 gld_lds, no wait)
    {
        const _Float16* as  = Aswz + achunk0;
        const _Float16* bhs = bthi + bchunk0;
        #pragma unroll
        for (int p = 0; p < 2; ++p) {
            gld_lds16(as  + p * 2048 + ge0, &Ah[0][p * 2048 + le0]);
            gld_lds16(bhs + p * 2048 + ge0, &Bh[0][p * 2048 + le0]);
        }
    }

    for (int ks = 0; ks < KS; ++ks) {
        const int cur = ks & 1;
        if (ks + 1 < KS) {
            // prefetch tile ks+1 into the other buffer; leave it in flight
            const _Float16* as  = Aswz + achunk0 + ((size_t)(ks + 1) << 12);
            const _Float16* bhs = bthi + bchunk0 + ((size_t)(ks + 1) << 12);
            #pragma unroll
            for (int p = 0; p < 2; ++p) {
                gld_lds16(as  + p * 2048 + ge0, &Ah[cur ^ 1][p * 2048 + le0]);
                gld_lds16(bhs + p * 2048 + ge0, &Bh[cur ^ 1][p * 2048 + le0]);
            }
            asm volatile("s_waitcnt vmcnt(4)" ::: "memory");   // tile ks landed; prefetch in flight
        } else {
            asm volatile("s_waitcnt vmcnt(0)" ::: "memory");
        }
        __builtin_amdgcn_s_barrier();

        h16x8 af[4], bfh[4];
        #pragma unroll
        for (int m = 0; m < 4; ++m) {
            int row = wr * 64 + m * 16 + lr;
            af[m] = *(const h16x8*)&Ah[cur][kq * 1024 + row * 8];
        }
        #pragma unroll
        for (int n = 0; n < 4; ++n) {
            int col = wc * 64 + n * 16 + lr;
            bfh[n] = *(const h16x8*)&Bh[cur][kq * 1024 + col * 8];
        }
        #pragma unroll
        for (int m = 0; m < 4; ++m)
            #pragma unroll
            for (int n = 0; n < 4; ++n)
                acc[m][n] = __builtin_amdgcn_mfma_f32_16x16x32_f16(af[m], bfh[n], acc[m][n], 0, 0, 0);

        asm volatile("s_waitcnt lgkmcnt(0)" ::: "memory");     // my ds_reads done
        __builtin_amdgcn_s_barrier();                          // safe to overwrite buf[cur] next iter
    }

    // ---- epilogue A: attention-score dot products
    float aS[4], aD[4];
    #pragma unroll
    for (int n = 0; n < 4; ++n) {
        int c = c0 + wc * 64 + n * 16 + lr;
        aS[n] = asr[c];
        aD[n] = adr[c];
    }
    __syncthreads();
    if (t < 128) { rS[t] = 0.f; rD[t] = 0.f; }
    __syncthreads();
    #pragma unroll
    for (int m = 0; m < 4; ++m) {
        #pragma unroll
        for (int j = 0; j < 4; ++j) {
            float ps = 0.f, pd = 0.f;
            #pragma unroll
            for (int n = 0; n < 4; ++n) {
                float v = acc[m][n][j];
                ps += v * aS[n];
                pd += v * aD[n];
            }
            #pragma unroll
            for (int off = 1; off < 16; off <<= 1) {
                ps += __shfl_xor(ps, off, 64);
                pd += __shfl_xor(pd, off, 64);
            }
            if (lr == 0) {
                int row = wr * 64 + m * 16 + kq * 4 + j;
                atomicAdd(&rS[row], ps);
                atomicAdd(&rD[row], pd);
            }
        }
    }
    __syncthreads();
    if (t < 128) {
        int r = r0 + t;
        if (r < M) {
            sSg[(size_t)r * H + head] = rS[t];
            sDg[(size_t)r * H + head] = rD[t];
        }
    }

    // ---- epilogue B: h -> fp16
    #pragma unroll
    for (int m = 0; m < 4; ++m) {
        int rowb = r0 + wr * 64 + m * 16 + kq * 4;
        #pragma unroll
        for (int n = 0; n < 4; ++n) {
            int col = c0 + wc * 64 + n * 16 + lr;
            #pragma unroll
            for (int j = 0; j < 4; ++j) {
                int r = rowb + j;
                if (r < M) C2[(size_t)r * Nc + col] = (_Float16)acc[m][n][j];
            }
        }
    }
}

// ---------------------------------------------------------------- fused edge-softmax + aggregation
// 4 waves/block, one node/wave, no block barriers.  deg<=CAP fast path: LDS alphas.
template<int H, int CPT, int CAP>
__launch_bounds__(256)
__global__ void k_attnagg(const _Float16* __restrict__ hb2, const float* __restrict__ s_src,
                          const float* __restrict__ s_dst, const int* __restrict__ row_start,
                          const int* __restrict__ csr, const float* __restrict__ bias,
                          _Float16* __restrict__ out) {
    const int W = H * 128;
    __shared__ float alds[4][CAP * H];
    const int wv = threadIdx.x >> 6;
    const int lane = threadIdx.x & 63;
    const int n = blockIdx.x * 4 + wv;
    if (n >= N_NODES) return;
    const int lo = row_start[n], hi = row_start[n + 1];
    const int deg = hi - lo;

    const int h1 = lane & (H - 1);
    const int eo = lane / H;
    const int EPI = 64 / H;
    float sd1 = s_dst[n * H + h1];
    const int c0 = lane * CPT;
    const int myh = c0 >> 7;
    float* al = &alds[wv][0];

    float acc[CPT];
    #pragma unroll
    for (int j = 0; j < CPT; ++j) acc[j] = 0.f;
    float invv;

    if (deg <= CAP) {
        // pass 1: gather scores once, store e, running max
        float mx = -INFINITY;
        for (int q = eo; q < deg; q += EPI) {
            float e = lrelu(s_src[csr[lo + q] * H + h1] + sd1);
            al[q * H + h1] = e;
            mx = fmaxf(mx, e);
        }
        #pragma unroll
        for (int off = H; off < 64; off <<= 1) mx = fmaxf(mx, __shfl_xor(mx, off, 64));
        // pass 2: exp in place + sum
        float sum = 0.f;
        for (int q = eo; q < deg; q += EPI) {
            float ex = expf(al[q * H + h1] - mx);
            al[q * H + h1] = ex;
            sum += ex;
        }
        #pragma unroll
        for (int off = H; off < 64; off <<= 1) sum += __shfl_xor(sum, off, 64);
        invv = __shfl(1.f / sum, myh, 64);
        asm volatile("s_waitcnt lgkmcnt(0)" ::: "memory");
        __builtin_amdgcn_sched_barrier(0);

        // phase 2: padded unroll-16 row gather
        for (int q = 0; q < deg; q += 16) {
            int s[16];
            float a[16];
            #pragma unroll
            for (int j = 0; j < 16; ++j) {
                int qq = q + j;
                int qc = qq < deg ? qq : deg - 1;
                s[j] = csr[lo + qc];
                a[j] = (qq < deg) ? al[qc * H + myh] : 0.f;
            }
            if constexpr (CPT == 8) {
                uint4 v[16];
                #pragma unroll
                for (int j = 0; j < 16; ++j) v[j] = *(const uint4*)&hb2[(size_t)s[j] * W + c0];
                #pragma unroll
                for (int j = 0; j < 16; ++j) {
                    float2 x0 = h2f2(v[j].x), x1 = h2f2(v[j].y), x2 = h2f2(v[j].z), x3 = h2f2(v[j].w);
                    acc[0] += a[j]*x0.x; acc[1] += a[j]*x0.y; acc[2] += a[j]*x1.x; acc[3] += a[j]*x1.y;
                    acc[4] += a[j]*x2.x; acc[5] += a[j]*x2.y; acc[6] += a[j]*x3.x; acc[7] += a[j]*x3.y;
                }
            } else {
                unsigned v[16];
                #pragma unroll
                for (int j = 0; j < 16; ++j) v[j] = *(const unsigned*)&hb2[(size_t)s[j] * W + c0];
                #pragma unroll
                for (int j = 0; j < 16; ++j) {
                    float2 x = h2f2(v[j]);
                    acc[0] += a[j]*x.x; acc[1] += a[j]*x.y;
                }
            }
        }
    } else {
        // fallback (deg > CAP): inline recompute path
        float mx = -INFINITY;
        for (int p = lo + eo; p < hi; p += EPI) {
            float e = lrelu(s_src[csr[p] * H + h1] + sd1);
            mx = fmaxf(mx, e);
        }
        #pragma unroll
        for (int off = H; off < 64; off <<= 1) mx = fmaxf(mx, __shfl_xor(mx, off, 64));
        float sum = 0.f;
        for (int p = lo + eo; p < hi; p += EPI) {
            float e = lrelu(s_src[csr[p] * H + h1] + sd1);
            sum += expf(e - mx);
        }
        #pragma unroll
        for (int off = H; off < 64; off <<= 1) sum += __shfl_xor(sum, off, 64);
        float inv = 1.f / sum;
        float mxv = __shfl(mx, myh, 64);
        invv = __shfl(inv, myh, 64);
        float sdv = __shfl(sd1, myh, 64);
        for (int p = lo; p < hi; ++p) {
            int s0 = csr[p];
            float a0 = expf(lrelu(s_src[s0 * H + myh] + sdv) - mxv);
            if constexpr (CPT == 8) {
                uint4 v0 = *(const uint4*)&hb2[(size_t)s0 * W + c0];
                float2 x0 = h2f2(v0.x), x1 = h2f2(v0.y), x2 = h2f2(v0.z), x3 = h2f2(v0.w);
                acc[0] += a0*x0.x; acc[1] += a0*x0.y; acc[2] += a0*x1.x; acc[3] += a0*x1.y;
                acc[4] += a0*x2.x; acc[5] += a0*x2.y; acc[6] += a0*x3.x; acc[7] += a0*x3.y;
            } else {
                float2 x = h2f2(*(const unsigned*)&hb2[(size_t)s0 * W + c0]);
                acc[0] += a0*x.x; acc[1] += a0*x.y;
            }
        }
    }

    union { _Float16 h[CPT]; uint4 u4; unsigned u1; } pk;
    #pragma unroll
    for (int j = 0; j < CPT; ++j) pk.h[j] = (_Float16)(fmaf(acc[j], invv, bias[c0 + j]));
    if constexpr (CPT == 8)
        *(uint4*)&out[(size_t)n * W + c0] = pk.u4;
    else
        *(unsigned*)&out[(size_t)n * W + c0] = pk.u1;
}

// ---------------------------------------------------------------- BatchNorm stats (fp16 input)
__global__ void k_bnstat2(const _Float16* __restrict__ x, float* __restrict__ bnsum,
                          float* __restrict__ bnsq, int W) {
    const int RPB = 64;
    int t  = threadIdx.x;             // W/2 threads
    int r0 = blockIdx.x * RPB;
    int r1 = min(r0 + RPB, N_NODES);
    float s0 = 0.f, q0 = 0.f, s1 = 0.f, q1 = 0.f;
    for (int r = r0; r < r1; ++r) {
        float2 v = h2f2(*(const unsigned*)&x[(size_t)r * W + 2 * t]);
        s0 += v.x; q0 += v.x * v.x;
        s1 += v.y; q1 += v.y * v.y;
    }
    atomicAdd(&bnsum[2*t],   s0);
    atomicAdd(&bnsq[2*t],    q0);
    atomicAdd(&bnsum[2*t+1], s1);
    atomicAdd(&bnsq[2*t+1],  q1);
}

// ---------------------------------------------------------------- global mean pool (fp16 in, fused BN+ELU)
__global__ void k_pool(const _Float16* __restrict__ x, const int* __restrict__ batch,
                       const float* __restrict__ scale, const float* __restrict__ shift,
                       float* __restrict__ out) {
    int g = blockIdx.x;               // 256
    int f = threadIdx.x;              // 128
    int a = 0, b = N_NODES;
    while (a < b) { int m = (a + b) >> 1; if (batch[m] < g) a = m + 1; else b = m; }
    int lo = a;
    b = N_NODES;
    while (a < b) { int m = (a + b) >> 1; if (batch[m] < g + 1) a = m + 1; else b = m; }
    int hi = a;
    float sc = scale[f], sh = shift[f];
    float s = 0.f;
    for (int r = lo; r < hi; ++r) {
        float v = (float)x[(size_t)r * 128 + f];
        float y = fmaf(v, sc, sh);
        s += (y > 0.f) ? y : expm1f(y);
    }
    int cnt = hi - lo;
    out[g * 128 + f] = s / (float)(cnt > 0 ? cnt : 1);
}

// ---------------------------------------------------------------- launch
extern "C" void kernel_launch(void* const* d_in, const int* in_sizes, int n_in,
                              void* d_out, int out_size, void* d_ws, size_t ws_size,
                              hipStream_t stream) {
    const float* x     = (const float*)d_in[0];
    const int*   ei    = (const int*)d_in[1];
    const int*   batch = (const int*)d_in[2];
    const float* Wm[3]  = {(const float*)d_in[3],  (const float*)d_in[9],  (const float*)d_in[15]};
    const float* asr[3] = {(const float*)d_in[4],  (const float*)d_in[10], (const float*)d_in[16]};
    const float* adr[3] = {(const float*)d_in[5],  (const float*)d_in[11], (const float*)d_in[17]};
    const float* bia[3] = {(const float*)d_in[6],  (const float*)d_in[12], (const float*)d_in[18]};
    const float* gam[3] = {(const float*)d_in[7],  (const float*)d_in[13], (const float*)d_in[19]};
    const float* bet[3] = {(const float*)d_in[8],  (const float*)d_in[14], (const float*)d_in[20]};

    char* w = (char*)d_ws;
    auto alloc = [&](size_t bytes) -> void* {
        void* p = (void*)w;
        w += (bytes + 255) & ~(size_t)255;
        return p;
    };
    _Float16* act2   = (_Float16*)alloc((size_t)N_NODES * 512 * 2);
    _Float16* act128 = (_Float16*)alloc((size_t)N_NODES * 128 * 2);
    _Float16* hb2    = (_Float16*)alloc((size_t)N_NODES * 512 * 2);
    _Float16* Aswz   = (_Float16*)alloc((size_t)NPAD * 512 * 2);
    int* csr_src   = (int*)alloc((size_t)EP * 4);
    int* row_start = (int*)alloc((size_t)(N_NODES + 1) * 4);
    int* deg       = (int*)alloc((size_t)N_NODES * 4);
    int* cursor    = (int*)alloc((size_t)N_NODES * 4);
    float* s_src = (float*)alloc((size_t)N_NODES * 4 * 4);
    float* s_dst = (float*)alloc((size_t)N_NODES * 4 * 4);
    float* bn    = (float*)alloc(1024 * 4);
    float* scl   = (float*)alloc(512 * 4);
    float* shf   = (float*)alloc(512 * 4);
    int* totals  = (int*)alloc(64 * 4);
    _Float16* bthi = (_Float16*)alloc((size_t)512 * 512 * 2);

    // ---- CSR by dst (shared by all 3 layers)
    hipMemsetAsync(deg, 0, (size_t)N_NODES * 4, stream);
    hipMemsetAsync(cursor, 0, (size_t)N_NODES * 4, stream);
    k_hist<<<512, 256, 0, stream>>>(ei, deg);
    k_scan1<<<(N_NODES + 1023) / 1024, 1024, 0, stream>>>(deg, row_start, totals);
    k_scan2<<<1, 64, 0, stream>>>(totals, (N_NODES + 1023) / 1024);
    k_scan3<<<(N_NODES + 255) / 256, 256, 0, stream>>>(row_start, totals);
    k_scatter<<<512, 256, 0, stream>>>(ei, row_start, cursor, csr_src);

    auto layer = [&](int K, int li, int H, bool first, _Float16* outAct) {
        int Wd = H * 128;
        int lgKS = (K == 512) ? 4 : 2;
        int tot8 = (K * Wd) >> 3;
        k_cvtW<<<(tot8 + 255) / 256, 256, 0, stream>>>(Wm[li], bthi, Wd, lgKS);
        int ptot = NPAD * (K >> 3);
        if (first)
            k_prepA0<<<(ptot + 255) / 256, 256, 0, stream>>>(x, Aswz, K, lgKS);
        else
            k_prepA1<<<(ptot + 255) / 256, 256, 0, stream>>>(act2, scl, shf, Aswz, K, lgKS);
        dim3 gg(NPAD / 128, Wd / 128);
        k_gemm_f16<<<gg, 256, 0, stream>>>(Aswz, bthi, hb2, s_src, s_dst,
                                           asr[li], adr[li], N_NODES, K, Wd);
        int nb = (N_NODES + 3) / 4;
        if (H == 4)
            k_attnagg<4, 8, 256><<<nb, 256, 0, stream>>>(hb2, s_src, s_dst, row_start, csr_src,
                                                         bia[li], outAct);
        else
            k_attnagg<1, 2, 256><<<nb, 256, 0, stream>>>(hb2, s_src, s_dst, row_start, csr_src,
                                                         bia[li], outAct);
        hipMemsetAsync(bn, 0, 1024 * 4, stream);
        k_bnstat2<<<(N_NODES + 63) / 64, Wd / 2, 0, stream>>>(outAct, bn, bn + 512, Wd);
        k_bnprep<<<(Wd + 255) / 256, 256, 0, stream>>>(bn, bn + 512, gam[li], bet[li], scl, shf, Wd);
    };

    layer(128, 0, 4, true,  act2);     // x -> act2 [N,512] fp16 (pre-BN)
    layer(512, 1, 4, false, act2);     // BN/ELU via scale/shift in prepA1; -> act2
    layer(512, 2, 1, false, act128);   // -> act128 [N,128] fp16 (pre-BN)

    k_pool<<<G_GRAPHS, 128, 0, stream>>>(act128, batch, scl, shf, (float*)d_out);
}

// Round 12
// 844.133 us; speedup vs baseline: 1.0382x; 1.0382x over previous
//
#include <hip/hip_runtime.h>
#include <math.h>
#include <stdint.h>

#define N_NODES 50000
#define NPAD    50048            // 391 * 128
#define N_EDGES 800000
#define EP      (N_EDGES + N_NODES)   // 850000 edges incl self-loops
#define G_GRAPHS 256
#define BN_EPS   1e-5f
#define NEG_SLOPE 0.2f

typedef float f32x4 __attribute__((ext_vector_type(4)));
typedef _Float16 h16x8 __attribute__((ext_vector_type(8)));

static __device__ __forceinline__ float lrelu(float x) {
    return x > 0.f ? x : NEG_SLOPE * x;
}

static __device__ __forceinline__ void gld_lds16(const void* g, void* l) {
    __builtin_amdgcn_global_load_lds((const __attribute__((address_space(1))) void*)g,
                                     (__attribute__((address_space(3))) void*)l, 16, 0, 0);
}

static __device__ __forceinline__ float2 h2f2(unsigned u) {
    union { unsigned u; _Float16 h[2]; } c;
    c.u = u;
    return make_float2((float)c.h[0], (float)c.h[1]);
}

// ---------------------------------------------------------------- CSR build
__global__ void k_hist(const int* __restrict__ ei, int* __restrict__ deg) {
    int stride = gridDim.x * blockDim.x;
    for (int e = blockIdx.x * blockDim.x + threadIdx.x; e < EP; e += stride) {
        int d = (e < N_EDGES) ? ei[N_EDGES + e] : (e - N_EDGES);
        atomicAdd(&deg[d], 1);
    }
}

__global__ void k_scan1(const int* __restrict__ deg, int* __restrict__ row_start,
                        int* __restrict__ totals) {
    __shared__ int buf[1024];
    int t = threadIdx.x;
    int i = blockIdx.x * 1024 + t;
    int v = (i < N_NODES) ? deg[i] : 0;
    buf[t] = v;
    __syncthreads();
    for (int off = 1; off < 1024; off <<= 1) {
        int add = (t >= off) ? buf[t - off] : 0;
        __syncthreads();
        buf[t] += add;
        __syncthreads();
    }
    if (i < N_NODES) row_start[i] = buf[t] - v;     // exclusive
    if (t == 1023) totals[blockIdx.x] = buf[t];
}

__global__ void k_scan2(int* __restrict__ totals, int nb) {
    if (threadIdx.x == 0 && blockIdx.x == 0) {
        int run = 0;
        for (int i = 0; i < nb; ++i) { int v = totals[i]; totals[i] = run; run += v; }
    }
}

__global__ void k_scan3(int* __restrict__ row_start, const int* __restrict__ totals) {
    int i = blockIdx.x * blockDim.x + threadIdx.x;
    if (i < N_NODES) row_start[i] += totals[i >> 10];
    if (i == 0) row_start[N_NODES] = EP;
}

__global__ void k_scatter(const int* __restrict__ ei, const int* __restrict__ row_start,
                          int* __restrict__ cursor, int* __restrict__ csr_src) {
    int stride = gridDim.x * blockDim.x;
    for (int e = blockIdx.x * blockDim.x + threadIdx.x; e < EP; e += stride) {
        int s, d;
        if (e < N_EDGES) { s = ei[e]; d = ei[N_EDGES + e]; }
        else             { s = d = e - N_EDGES; }
        int pos = row_start[d] + atomicAdd(&cursor[d], 1);
        csr_src[pos] = s;
    }
}

// ---------------------------------------------------------------- weight convert (f16, pre-swizzled chunks)
// source-linear (coalesced reads; scattered writes are fire-and-forget) — R10-proven form
__global__ void k_cvtW(const float* __restrict__ W, _Float16* __restrict__ bthi,
                       int Nc, int nsh, int KS) {
    int i = blockIdx.x * 256 + threadIdx.x;
    if (i >= (KS << 5) * Nc) return;
    int k = i >> nsh;
    int n = i & (Nc - 1);
    int c = n >> 7, col = n & 127;
    int ks = k >> 5, kq = (k >> 3) & 3, j = k & 7;
    size_t idx = ((size_t)(c * KS + ks) << 12) + (kq << 10) + (col << 3) + j;
    bthi[idx] = (_Float16)W[i];
}

// ---------------------------------------------------------------- BN scale/shift prep (tiny, 1 launch)
__global__ void k_bnprep(const float* __restrict__ bnsum, const float* __restrict__ bnsq,
                         const float* __restrict__ gamma, const float* __restrict__ beta,
                         float* __restrict__ scale, float* __restrict__ shift, int W) {
    int f = blockIdx.x * 256 + threadIdx.x;
    if (f >= W) return;
    const float invN = 1.f / (float)N_NODES;
    float mean = bnsum[f] * invN;
    float var  = bnsq[f] * invN - mean * mean;
    float sc = gamma[f] * rsqrtf(var + BN_EPS);
    scale[f] = sc;
    shift[f] = beta[f] - mean * sc;
}

// ---------------------------------------------------------------- A prep: fp32 x -> f16 swizzled chunks (source-linear)
__global__ void k_prepA0(const float* __restrict__ x, _Float16* __restrict__ Aswz,
                         int K, int s8, int KS) {
    int i = blockIdx.x * 256 + threadIdx.x;
    if (i >= NPAD * (K >> 3)) return;
    int r  = i >> s8;
    int c8 = i & ((K >> 3) - 1);
    int k  = c8 << 3;
    union { _Float16 h[8]; uint4 u; } pk;
    if (r < N_NODES) {
        float4 a0 = *(const float4*)&x[(size_t)r * K + k];
        float4 a1 = *(const float4*)&x[(size_t)r * K + k + 4];
        pk.h[0]=(_Float16)a0.x; pk.h[1]=(_Float16)a0.y; pk.h[2]=(_Float16)a0.z; pk.h[3]=(_Float16)a0.w;
        pk.h[4]=(_Float16)a1.x; pk.h[5]=(_Float16)a1.y; pk.h[6]=(_Float16)a1.z; pk.h[7]=(_Float16)a1.w;
    } else {
        pk.u.x = pk.u.y = pk.u.z = pk.u.w = 0u;
    }
    int rb = r >> 7, row = r & 127;
    int ks = k >> 5, kq = (k >> 3) & 3;
    size_t idx = ((size_t)(rb * KS + ks) << 12) + (kq << 10) + (row << 3);
    *(uint4*)&Aswz[idx] = pk.u;
}

// ---------------------------------------------------------------- A prep: fp16 act + BN(scale/shift) + ELU (source-linear)
__global__ void k_prepA1(const _Float16* __restrict__ act, const float* __restrict__ scale,
                         const float* __restrict__ shift, _Float16* __restrict__ Aswz,
                         int K, int s8, int KS) {
    int i = blockIdx.x * 256 + threadIdx.x;
    if (i >= NPAD * (K >> 3)) return;
    int r  = i >> s8;
    int c8 = i & ((K >> 3) - 1);
    int k  = c8 << 3;
    union { _Float16 h[8]; uint4 u; } pk;
    if (r < N_NODES) {
        uint4 v = *(const uint4*)&act[(size_t)r * K + k];
        float4 sc0 = *(const float4*)&scale[k];
        float4 sc1 = *(const float4*)&scale[k + 4];
        float4 sh0 = *(const float4*)&shift[k];
        float4 sh1 = *(const float4*)&shift[k + 4];
        float2 p0 = h2f2(v.x), p1 = h2f2(v.y), p2 = h2f2(v.z), p3 = h2f2(v.w);
        float y;
        y = fmaf(p0.x, sc0.x, sh0.x); pk.h[0] = (_Float16)(y > 0.f ? y : expm1f(y));
        y = fmaf(p0.y, sc0.y, sh0.y); pk.h[1] = (_Float16)(y > 0.f ? y : expm1f(y));
        y = fmaf(p1.x, sc0.z, sh0.z); pk.h[2] = (_Float16)(y > 0.f ? y : expm1f(y));
        y = fmaf(p1.y, sc0.w, sh0.w); pk.h[3] = (_Float16)(y > 0.f ? y : expm1f(y));
        y = fmaf(p2.x, sc1.x, sh1.x); pk.h[4] = (_Float16)(y > 0.f ? y : expm1f(y));
        y = fmaf(p2.y, sc1.y, sh1.y); pk.h[5] = (_Float16)(y > 0.f ? y : expm1f(y));
        y = fmaf(p3.x, sc1.z, sh1.z); pk.h[6] = (_Float16)(y > 0.f ? y : expm1f(y));
        y = fmaf(p3.y, sc1.w, sh1.w); pk.h[7] = (_Float16)(y > 0.f ? y : expm1f(y));
    } else {
        pk.u.x = pk.u.y = pk.u.z = pk.u.w = 0u;
    }
    int rb = r >> 7, row = r & 127;
    int ks = k >> 5, kq = (k >> 3) & 3;
    size_t idx = ((size_t)(rb * KS + ks) << 12) + (kq << 10) + (row << 3);
    *(uint4*)&Aswz[idx] = pk.u;
}

// ---------------------------------------------------------------- f16 single-pass MFMA GEMM,
// double-buffered LDS + counted vmcnt (prefetch stays in flight across MFMA).
__launch_bounds__(256)
__global__ void k_gemm_f16(const _Float16* __restrict__ Aswz, const _Float16* __restrict__ bthi,
                           _Float16* __restrict__ C2,
                           float* __restrict__ sSg, float* __restrict__ sDg,
                           const float* __restrict__ asr, const float* __restrict__ adr,
                           int M, int K, int Nc) {
    __shared__ _Float16 Ah[2][4096], Bh[2][4096];   // 32 KB double-buffered
    __shared__ float rS[128], rD[128];
    const int t    = threadIdx.x;
    const int lane = t & 63, wv = t >> 6;
    const int wr = wv >> 1, wc = wv & 1;
    const int lr = lane & 15, kq = lane >> 4;
    const int r0 = blockIdx.x * 128, c0 = blockIdx.y * 128;
    const int KS = K >> 5;
    const int H = Nc >> 7;
    const int head = blockIdx.y;

    const size_t achunk0 = (size_t)blockIdx.x * KS * 4096;
    const size_t bchunk0 = (size_t)blockIdx.y * KS * 4096;
    const int ge0 = wv * 512 + lane * 8;
    const int le0 = wv * 512;

    f32x4 acc[4][4];
    #pragma unroll
    for (int m = 0; m < 4; ++m)
        #pragma unroll
        for (int n = 0; n < 4; ++n) {
            acc[m][n][0] = 0.f; acc[m][n][1] = 0.f;
            acc[m][n][2] = 0.f; acc[m][n][3] = 0.f;
        }

    // prologue: issue tile 0 into buffer 0 (4 gld_lds, no wait)
    {
        const _Float16* as  = Aswz + achunk0;
        const _Float16* bhs = bthi + bchunk0;
        #pragma unroll
        for (int p = 0; p < 2; ++p) {
            gld_lds16(as  + p * 2048 + ge0, &Ah[0][p * 2048 + le0]);
            gld_lds16(bhs + p * 2048 + ge0, &Bh[0][p * 2048 + le0]);
        }
    }

    for (int ks = 0; ks < KS; ++ks) {
        const int cur = ks & 1;
        if (ks + 1 < KS) {
            // prefetch tile ks+1 into the other buffer; leave it in flight
            const _Float16* as  = Aswz + achunk0 + ((size_t)(ks + 1) << 12);
            const _Float16* bhs = bthi + bchunk0 + ((size_t)(ks + 1) << 12);
            #pragma unroll
            for (int p = 0; p < 2; ++p) {
                gld_lds16(as  + p * 2048 + ge0, &Ah[cur ^ 1][p * 2048 + le0]);
                gld_lds16(bhs + p * 2048 + ge0, &Bh[cur ^ 1][p * 2048 + le0]);
            }
            asm volatile("s_waitcnt vmcnt(4)" ::: "memory");   // tile ks landed; prefetch in flight
        } else {
            asm volatile("s_waitcnt vmcnt(0)" ::: "memory");
        }
        __builtin_amdgcn_s_barrier();

        h16x8 af[4], bfh[4];
        #pragma unroll
        for (int m = 0; m < 4; ++m) {
            int row = wr * 64 + m * 16 + lr;
            af[m] = *(const h16x8*)&Ah[cur][kq * 1024 + row * 8];
        }
        #pragma unroll
        for (int n = 0; n < 4; ++n) {
            int col = wc * 64 + n * 16 + lr;
            bfh[n] = *(const h16x8*)&Bh[cur][kq * 1024 + col * 8];
        }
        #pragma unroll
        for (int m = 0; m < 4; ++m)
            #pragma unroll
            for (int n = 0; n < 4; ++n)
                acc[m][n] = __builtin_amdgcn_mfma_f32_16x16x32_f16(af[m], bfh[n], acc[m][n], 0, 0, 0);

        asm volatile("s_waitcnt lgkmcnt(0)" ::: "memory");     // my ds_reads done
        __builtin_amdgcn_s_barrier();                          // safe to overwrite buf[cur] next iter
    }

    // ---- epilogue A: attention-score dot products
    float aS[4], aD[4];
    #pragma unroll
    for (int n = 0; n < 4; ++n) {
        int c = c0 + wc * 64 + n * 16 + lr;
        aS[n] = asr[c];
        aD[n] = adr[c];
    }
    __syncthreads();
    if (t < 128) { rS[t] = 0.f; rD[t] = 0.f; }
    __syncthreads();
    #pragma unroll
    for (int m = 0; m < 4; ++m) {
        #pragma unroll
        for (int j = 0; j < 4; ++j) {
            float ps = 0.f, pd = 0.f;
            #pragma unroll
            for (int n = 0; n < 4; ++n) {
                float v = acc[m][n][j];
                ps += v * aS[n];
                pd += v * aD[n];
            }
            #pragma unroll
            for (int off = 1; off < 16; off <<= 1) {
                ps += __shfl_xor(ps, off, 64);
                pd += __shfl_xor(pd, off, 64);
            }
            if (lr == 0) {
                int row = wr * 64 + m * 16 + kq * 4 + j;
                atomicAdd(&rS[row], ps);
                atomicAdd(&rD[row], pd);
            }
        }
    }
    __syncthreads();
    if (t < 128) {
        int r = r0 + t;
        if (r < M) {
            sSg[(size_t)r * H + head] = rS[t];
            sDg[(size_t)r * H + head] = rD[t];
        }
    }

    // ---- epilogue B: h -> fp16
    #pragma unroll
    for (int m = 0; m < 4; ++m) {
        int rowb = r0 + wr * 64 + m * 16 + kq * 4;
        #pragma unroll
        for (int n = 0; n < 4; ++n) {
            int col = c0 + wc * 64 + n * 16 + lr;
            #pragma unroll
            for (int j = 0; j < 4; ++j) {
                int r = rowb + j;
                if (r < M) C2[(size_t)r * Nc + col] = (_Float16)acc[m][n][j];
            }
        }
    }
}

// ---------------------------------------------------------------- fused edge-softmax + aggregation
// 4 waves/block, one node/wave, no block barriers.  deg<=CAP fast path: LDS alphas.
template<int H, int CPT, int CAP>
__launch_bounds__(256)
__global__ void k_attnagg(const _Float16* __restrict__ hb2, const float* __restrict__ s_src,
                          const float* __restrict__ s_dst, const int* __restrict__ row_start,
                          const int* __restrict__ csr, const float* __restrict__ bias,
                          _Float16* __restrict__ out) {
    const int W = H * 128;
    __shared__ float alds[4][CAP * H];
    const int wv = threadIdx.x >> 6;
    const int lane = threadIdx.x & 63;
    const int n = blockIdx.x * 4 + wv;
    if (n >= N_NODES) return;
    const int lo = row_start[n], hi = row_start[n + 1];
    const int deg = hi - lo;

    const int h1 = lane & (H - 1);
    const int eo = lane / H;
    const int EPI = 64 / H;
    float sd1 = s_dst[n * H + h1];
    const int c0 = lane * CPT;
    const int myh = c0 >> 7;
    float* al = &alds[wv][0];

    float acc[CPT];
    #pragma unroll
    for (int j = 0; j < CPT; ++j) acc[j] = 0.f;
    float invv;

    if (deg <= CAP) {
        // pass 1: gather scores once, store e, running max
        float mx = -INFINITY;
        for (int q = eo; q < deg; q += EPI) {
            float e = lrelu(s_src[csr[lo + q] * H + h1] + sd1);
            al[q * H + h1] = e;
            mx = fmaxf(mx, e);
        }
        #pragma unroll
        for (int off = H; off < 64; off <<= 1) mx = fmaxf(mx, __shfl_xor(mx, off, 64));
        // pass 2: exp in place + sum
        float sum = 0.f;
        for (int q = eo; q < deg; q += EPI) {
            float ex = expf(al[q * H + h1] - mx);
            al[q * H + h1] = ex;
            sum += ex;
        }
        #pragma unroll
        for (int off = H; off < 64; off <<= 1) sum += __shfl_xor(sum, off, 64);
        invv = __shfl(1.f / sum, myh, 64);
        asm volatile("s_waitcnt lgkmcnt(0)" ::: "memory");
        __builtin_amdgcn_sched_barrier(0);

        // phase 2: padded unroll-16 row gather
        for (int q = 0; q < deg; q += 16) {
            int s[16];
            float a[16];
            #pragma unroll
            for (int j = 0; j < 16; ++j) {
                int qq = q + j;
                int qc = qq < deg ? qq : deg - 1;
                s[j] = csr[lo + qc];
                a[j] = (qq < deg) ? al[qc * H + myh] : 0.f;
            }
            if constexpr (CPT == 8) {
                uint4 v[16];
                #pragma unroll
                for (int j = 0; j < 16; ++j) v[j] = *(const uint4*)&hb2[(size_t)s[j] * W + c0];
                #pragma unroll
                for (int j = 0; j < 16; ++j) {
                    float2 x0 = h2f2(v[j].x), x1 = h2f2(v[j].y), x2 = h2f2(v[j].z), x3 = h2f2(v[j].w);
                    acc[0] += a[j]*x0.x; acc[1] += a[j]*x0.y; acc[2] += a[j]*x1.x; acc[3] += a[j]*x1.y;
                    acc[4] += a[j]*x2.x; acc[5] += a[j]*x2.y; acc[6] += a[j]*x3.x; acc[7] += a[j]*x3.y;
                }
            } else {
                unsigned v[16];
                #pragma unroll
                for (int j = 0; j < 16; ++j) v[j] = *(const unsigned*)&hb2[(size_t)s[j] * W + c0];
                #pragma unroll
                for (int j = 0; j < 16; ++j) {
                    float2 x = h2f2(v[j]);
                    acc[0] += a[j]*x.x; acc[1] += a[j]*x.y;
                }
            }
        }
    } else {
        // fallback (deg > CAP): inline recompute path
        float mx = -INFINITY;
        for (int p = lo + eo; p < hi; p += EPI) {
            float e = lrelu(s_src[csr[p] * H + h1] + sd1);
            mx = fmaxf(mx, e);
        }
        #pragma unroll
        for (int off = H; off < 64; off <<= 1) mx = fmaxf(mx, __shfl_xor(mx, off, 64));
        float sum = 0.f;
        for (int p = lo + eo; p < hi; p += EPI) {
            float e = lrelu(s_src[csr[p] * H + h1] + sd1);
            sum += expf(e - mx);
        }
        #pragma unroll
        for (int off = H; off < 64; off <<= 1) sum += __shfl_xor(sum, off, 64);
        float inv = 1.f / sum;
        float mxv = __shfl(mx, myh, 64);
        invv = __shfl(inv, myh, 64);
        float sdv = __shfl(sd1, myh, 64);
        for (int p = lo; p < hi; ++p) {
            int s0 = csr[p];
            float a0 = expf(lrelu(s_src[s0 * H + myh] + sdv) - mxv);
            if constexpr (CPT == 8) {
                uint4 v0 = *(const uint4*)&hb2[(size_t)s0 * W + c0];
                float2 x0 = h2f2(v0.x), x1 = h2f2(v0.y), x2 = h2f2(v0.z), x3 = h2f2(v0.w);
                acc[0] += a0*x0.x; acc[1] += a0*x0.y; acc[2] += a0*x1.x; acc[3] += a0*x1.y;
                acc[4] += a0*x2.x; acc[5] += a0*x2.y; acc[6] += a0*x3.x; acc[7] += a0*x3.y;
            } else {
                float2 x = h2f2(*(const unsigned*)&hb2[(size_t)s0 * W + c0]);
                acc[0] += a0*x.x; acc[1] += a0*x.y;
            }
        }
    }

    union { _Float16 h[CPT]; uint4 u4; unsigned u1; } pk;
    #pragma unroll
    for (int j = 0; j < CPT; ++j) pk.h[j] = (_Float16)(fmaf(acc[j], invv, bias[c0 + j]));
    if constexpr (CPT == 8)
        *(uint4*)&out[(size_t)n * W + c0] = pk.u4;
    else
        *(unsigned*)&out[(size_t)n * W + c0] = pk.u1;
}

// ---------------------------------------------------------------- BatchNorm stats (fp16 input)
__global__ void k_bnstat2(const _Float16* __restrict__ x, float* __restrict__ bnsum,
                          float* __restrict__ bnsq, int W) {
    const int RPB = 64;
    int t  = threadIdx.x;             // W/2 threads
    int r0 = blockIdx.x * RPB;
    int r1 = min(r0 + RPB, N_NODES);
    float s0 = 0.f, q0 = 0.f, s1 = 0.f, q1 = 0.f;
    for (int r = r0; r < r1; ++r) {
        float2 v = h2f2(*(const unsigned*)&x[(size_t)r * W + 2 * t]);
        s0 += v.x; q0 += v.x * v.x;
        s1 += v.y; q1 += v.y * v.y;
    }
    atomicAdd(&bnsum[2*t],   s0);
    atomicAdd(&bnsq[2*t],    q0);
    atomicAdd(&bnsum[2*t+1], s1);
    atomicAdd(&bnsq[2*t+1],  q1);
}

// ---------------------------------------------------------------- global mean pool (fp16 in, fused BN+ELU)
__global__ void k_pool(const _Float16* __restrict__ x, const int* __restrict__ batch,
                       const float* __restrict__ scale, const float* __restrict__ shift,
                       float* __restrict__ out) {
    int g = blockIdx.x;               // 256
    int f = threadIdx.x;              // 128
    int a = 0, b = N_NODES;
    while (a < b) { int m = (a + b) >> 1; if (batch[m] < g) a = m + 1; else b = m; }
    int lo = a;
    b = N_NODES;
    while (a < b) { int m = (a + b) >> 1; if (batch[m] < g + 1) a = m + 1; else b = m; }
    int hi = a;
    float sc = scale[f], sh = shift[f];
    float s = 0.f;
    for (int r = lo; r < hi; ++r) {
        float v = (float)x[(size_t)r * 128 + f];
        float y = fmaf(v, sc, sh);
        s += (y > 0.f) ? y : expm1f(y);
    }
    int cnt = hi - lo;
    out[g * 128 + f] = s / (float)(cnt > 0 ? cnt : 1);
}

// ---------------------------------------------------------------- launch
extern "C" void kernel_launch(void* const* d_in, const int* in_sizes, int n_in,
                              void* d_out, int out_size, void* d_ws, size_t ws_size,
                              hipStream_t stream) {
    const float* x     = (const float*)d_in[0];
    const int*   ei    = (const int*)d_in[1];
    const int*   batch = (const int*)d_in[2];
    const float* Wm[3]  = {(const float*)d_in[3],  (const float*)d_in[9],  (const float*)d_in[15]};
    const float* asr[3] = {(const float*)d_in[4],  (const float*)d_in[10], (const float*)d_in[16]};
    const float* adr[3] = {(const float*)d_in[5],  (const float*)d_in[11], (const float*)d_in[17]};
    const float* bia[3] = {(const float*)d_in[6],  (const float*)d_in[12], (const float*)d_in[18]};
    const float* gam[3] = {(const float*)d_in[7],  (const float*)d_in[13], (const float*)d_in[19]};
    const float* bet[3] = {(const float*)d_in[8],  (const float*)d_in[14], (const float*)d_in[20]};

    char* w = (char*)d_ws;
    auto alloc = [&](size_t bytes) -> void* {
        void* p = (void*)w;
        w += (bytes + 255) & ~(size_t)255;
        return p;
    };
    _Float16* act2   = (_Float16*)alloc((size_t)N_NODES * 512 * 2);
    _Float16* act128 = (_Float16*)alloc((size_t)N_NODES * 128 * 2);
    _Float16* hb2    = (_Float16*)alloc((size_t)N_NODES * 512 * 2);
    _Float16* Aswz   = (_Float16*)alloc((size_t)NPAD * 512 * 2);
    int* csr_src   = (int*)alloc((size_t)EP * 4);
    int* row_start = (int*)alloc((size_t)(N_NODES + 1) * 4);
    int* deg       = (int*)alloc((size_t)N_NODES * 4);
    int* cursor    = (int*)alloc((size_t)N_NODES * 4);
    float* s_src = (float*)alloc((size_t)N_NODES * 4 * 4);
    float* s_dst = (float*)alloc((size_t)N_NODES * 4 * 4);
    float* bn    = (float*)alloc(1024 * 4);
    float* scl   = (float*)alloc(512 * 4);
    float* shf   = (float*)alloc(512 * 4);
    int* totals  = (int*)alloc(64 * 4);
    _Float16* bthi = (_Float16*)alloc((size_t)512 * 512 * 2);

    // ---- CSR by dst (shared by all 3 layers)
    hipMemsetAsync(deg, 0, (size_t)N_NODES * 4, stream);
    hipMemsetAsync(cursor, 0, (size_t)N_NODES * 4, stream);
    k_hist<<<512, 256, 0, stream>>>(ei, deg);
    k_scan1<<<(N_NODES + 1023) / 1024, 1024, 0, stream>>>(deg, row_start, totals);
    k_scan2<<<1, 64, 0, stream>>>(totals, (N_NODES + 1023) / 1024);
    k_scan3<<<(N_NODES + 255) / 256, 256, 0, stream>>>(row_start, totals);
    k_scatter<<<512, 256, 0, stream>>>(ei, row_start, cursor, csr_src);

    auto layer = [&](int K, int li, int H, bool first, _Float16* outAct) {
        int Wd = H * 128;
        int nsh = (Wd == 512) ? 9 : 7;
        int KS = K >> 5;
        int s8 = (K == 512) ? 6 : 4;   // log2(K/8)
        int tot = K * Wd;
        k_cvtW<<<(tot + 255) / 256, 256, 0, stream>>>(Wm[li], bthi, Wd, nsh, KS);
        int ptot = NPAD * (K >> 3);
        if (first)
            k_prepA0<<<(ptot + 255) / 256, 256, 0, stream>>>(x, Aswz, K, s8, KS);
        else
            k_prepA1<<<(ptot + 255) / 256, 256, 0, stream>>>(act2, scl, shf, Aswz, K, s8, KS);
        dim3 gg(NPAD / 128, Wd / 128);
        k_gemm_f16<<<gg, 256, 0, stream>>>(Aswz, bthi, hb2, s_src, s_dst,
                                           asr[li], adr[li], N_NODES, K, Wd);
        int nb = (N_NODES + 3) / 4;
        if (H == 4)
            k_attnagg<4, 8, 256><<<nb, 256, 0, stream>>>(hb2, s_src, s_dst, row_start, csr_src,
                                                         bia[li], outAct);
        else
            k_attnagg<1, 2, 256><<<nb, 256, 0, stream>>>(hb2, s_src, s_dst, row_start, csr_src,
                                                         bia[li], outAct);
        hipMemsetAsync(bn, 0, 1024 * 4, stream);
        k_bnstat2<<<(N_NODES + 63) / 64, Wd / 2, 0, stream>>>(outAct, bn, bn + 512, Wd);
        k_bnprep<<<(Wd + 255) / 256, 256, 0, stream>>>(bn, bn + 512, gam[li], bet[li], scl, shf, Wd);
    };

    layer(128, 0, 4, true,  act2);     // x -> act2 [N,512] fp16 (pre-BN)
    layer(512, 1, 4, false, act2);     // BN/ELU via scale/shift in prepA1; -> act2
    layer(512, 2, 1, false, act128);   // -> act128 [N,128] fp16 (pre-BN)

    k_pool<<<G_GRAPHS, 128, 0, stream>>>(act128, batch, scl, shf, (float*)d_out);
}